// Round 12
// baseline (2200.684 us; speedup 1.0000x reference)
//
#include <hip/hip_runtime.h>
#include <cmath>

#define BATCH  2
#define SEQ    2048
#define DMODEL 1024
#define NHEAD  16
#define HDIM   64
#define KTOP   8
#define KKEEP  10   // top-8 + slack for bitwise ties at the threshold

// KC=512 CONFIRMED bit-exact vs harness numpy reference (rounds 6/8-11 pass).
#define KC_PANEL 512

// ---------------------------------------------------------------------------
// Projection GEMM replicating OpenBLAS sgemm fp32 rounding (KC=512 panels).
// MODE 0: out in head layout [b][h][s][d]; MODE 1: flat [row][col].
// ---------------------------------------------------------------------------
template<int MODE>
__global__ __launch_bounds__(256)
void proj_gemm(const float* __restrict__ A, const float* __restrict__ W,
               const float* __restrict__ bias, float* __restrict__ outp)
{
    __shared__ float As[32][68];   // [k][m]
    __shared__ float Bs[32][68];   // [k][n]
    const int tid  = threadIdx.x;
    const int tx   = tid & 15, ty = tid >> 4;
    const int row0 = blockIdx.x * 64;
    const int col0 = blockIdx.y * 64;
    const int lm   = tid >> 2;          // 0..63
    const int lk   = (tid & 3) * 8;     // 0,8,16,24

    float acc[4][4] = {};   // open panel chain
    float sum[4][4] = {};   // closed panels

    for (int kb = 0; kb < DMODEL; kb += 32) {
        if (kb && (kb % KC_PANEL == 0)) {
            #pragma unroll
            for (int i = 0; i < 4; ++i)
                #pragma unroll
                for (int j = 0; j < 4; ++j) { sum[i][j] += acc[i][j]; acc[i][j] = 0.f; }
        }
        __syncthreads();
        const float* srcA = A + (size_t)(row0 + lm) * DMODEL + kb + lk;
        float4 a0 = *(const float4*)srcA;
        float4 a1 = *(const float4*)(srcA + 4);
        const float* srcB = W + (size_t)(col0 + lm) * DMODEL + kb + lk;
        float4 b0 = *(const float4*)srcB;
        float4 b1 = *(const float4*)(srcB + 4);
        As[lk+0][lm]=a0.x; As[lk+1][lm]=a0.y; As[lk+2][lm]=a0.z; As[lk+3][lm]=a0.w;
        As[lk+4][lm]=a1.x; As[lk+5][lm]=a1.y; As[lk+6][lm]=a1.z; As[lk+7][lm]=a1.w;
        Bs[lk+0][lm]=b0.x; Bs[lk+1][lm]=b0.y; Bs[lk+2][lm]=b0.z; Bs[lk+3][lm]=b0.w;
        Bs[lk+4][lm]=b1.x; Bs[lk+5][lm]=b1.y; Bs[lk+6][lm]=b1.z; Bs[lk+7][lm]=b1.w;
        __syncthreads();
        #pragma unroll
        for (int kk = 0; kk < 32; ++kk) {   // ascending k, fused-FMA chain
            float4 af = *(const float4*)&As[kk][ty*4];
            float4 bf = *(const float4*)&Bs[kk][tx*4];
            float a_[4] = {af.x, af.y, af.z, af.w};
            float b_[4] = {bf.x, bf.y, bf.z, bf.w};
            #pragma unroll
            for (int i = 0; i < 4; ++i)
                #pragma unroll
                for (int j = 0; j < 4; ++j)
                    acc[i][j] = fmaf(a_[i], b_[j], acc[i][j]);
        }
    }

    #pragma unroll
    for (int i = 0; i < 4; ++i) {
        const int row = row0 + ty*4 + i;
        const int bb  = row >> 11;
        const int ss  = row & (SEQ - 1);
        #pragma unroll
        for (int j = 0; j < 4; ++j) {
            const int col = col0 + tx*4 + j;
            float r = sum[i][j] + acc[i][j];   // close final panel
            r = r + bias[col];                 // bias == 0.0f: exact
            if constexpr (MODE == 1) {
                outp[(size_t)row * DMODEL + col] = r;
            } else {
                const int h = col >> 6, d = col & 63;
                outp[(((size_t)(bb*NHEAD + h))*SEQ + ss)*HDIM + d] = r;
            }
        }
    }
}

// ---------------------------------------------------------------------------
// Attention, lane = query row, waves split KEYS (occupancy fix for R11's
// 1-block/CU grid limit: 65536 rows = only 1024 row-waves; splitting keys
// 4-way gives 4096 waves = 16/CU).
//   block = 4 waves x 64 lanes, all covering the SAME 64 rows (rg);
//   wave w scans contiguous keys [w*512, (w+1)*512) -- ascending order, so
//   each partial top-10 has R6-verified tie semantics; 4-way merge with
//   (value, lower-index-wins) comparator reproduces the sequential scan
//   exactly -> bit-identical selection.
// K is read DIRECTLY from L2: wave-uniform broadcast float4 loads (1
// transaction/load). grid.x = bh so XCD = bh%8 -> K working set 4 heads
// x 0.5 MB = 2 MB, fits 4 MB per-XCD L2. NO LDS staging, NO barriers in
// the hot loop; LDS only for the final partial-list exchange (padded to
// 11 floats/row: 2-way bank access, free).
// PV: wave w computes output dims [w*16,(w+1)*16); fmaf order s=0..9
// ascending, weights 0 for non-kept slots (adding 0*v is bitwise exact).
// ---------------------------------------------------------------------------
__global__ __launch_bounds__(256, 4)
void attn_topk(const float* __restrict__ Qh, const float* __restrict__ Kh,
               const float* __restrict__ Vh, float* __restrict__ AO)
{
    __shared__ float Ls[4][64][KKEEP + 1];   // +1 pad: 11*4B lane stride
    __shared__ int   Li[4][64][KKEEP + 1];
    const int tid  = threadIdx.x;
    const int lane = tid & 63;
    const int w    = tid >> 6;          // 0..3 (key quarter / dim quarter)
    const int bh   = blockIdx.x;        // 0..31  (XCD = bh % 8)
    const int rg   = blockIdx.y;        // 0..31
    const int srow = rg * 64 + lane;    // this lane's query row
    const size_t hbase = (size_t)bh * SEQ * HDIM;
    const float* Q = Qh + hbase;
    const float* K = Kh + hbase;
    const float* V = Vh + hbase;

    // ---- this lane's q row -> VGPRs ----
    float q[64];
    {
        const float* qsrc = Q + (size_t)srow * HDIM;
        #pragma unroll
        for (int d4 = 0; d4 < 16; ++d4) {
            float4 t4 = *(const float4*)(qsrc + d4*4);
            q[d4*4+0]=t4.x; q[d4*4+1]=t4.y; q[d4*4+2]=t4.z; q[d4*4+3]=t4.w;
        }
    }

    // ---- lane-local top-KKEEP over this wave's 512-key range ----
    float tv[KKEEP]; int ti[KKEEP];
    #pragma unroll
    for (int s = 0; s < KKEEP; ++s) { tv[s] = -INFINITY; ti[s] = -1; }

    const int k0 = w * (SEQ/4);
    #pragma unroll 2
    for (int c = 0; c < SEQ/4; ++c) {
        const float* kb = K + (size_t)(k0 + c) * HDIM;   // wave-uniform addr
        float raw;
        {
            #pragma clang fp contract(off)
            float A0=0.f, A1=0.f, A2=0.f, A3=0.f;
            #pragma unroll
            for (int t = 0; t < 4; ++t) {   // 16-dim blocks, ascending
                float kv[16];
                #pragma unroll
                for (int f = 0; f < 4; ++f) {
                    float4 k4 = *(const float4*)(kb + t*16 + 4*f);  // broadcast
                    kv[f*4+0]=k4.x; kv[f*4+1]=k4.y; kv[f*4+2]=k4.z; kv[f*4+3]=k4.w;
                }
                const int u = t*16;
                A0 = q[u+0]*kv[0] + (q[u+4]*kv[4] + (q[u+8]*kv[8]   + (q[u+12]*kv[12] + A0)));
                A1 = q[u+1]*kv[1] + (q[u+5]*kv[5] + (q[u+9]*kv[9]   + (q[u+13]*kv[13] + A1)));
                A2 = q[u+2]*kv[2] + (q[u+6]*kv[6] + (q[u+10]*kv[10] + (q[u+14]*kv[14] + A2)));
                A3 = q[u+3]*kv[3] + (q[u+7]*kv[7] + (q[u+11]*kv[11] + (q[u+15]*kv[15] + A3)));
            }
            raw = (A0 + A1) + (A2 + A3);
        }
        const float cand = raw * 0.125f;     // /sqrt(64) exact
        if (cand > tv[KKEEP-1]) {            // lane-local sorted insert
            float v = cand; int ix = k0 + c;
            #pragma unroll
            for (int s = 0; s < KKEEP; ++s) {
                const bool gt = v > tv[s];
                const float otv = tv[s]; const int oti = ti[s];
                tv[s] = gt ? v  : otv;  ti[s] = gt ? ix  : oti;
                v     = gt ? otv : v;   ix    = gt ? oti : ix;
            }
        }
    }

    // ---- publish partial lists, one barrier ----
    #pragma unroll
    for (int s = 0; s < KKEEP; ++s) {
        Ls[w][lane][s] = tv[s];
        Li[w][lane][s] = ti[s];
    }
    __syncthreads();

    // ---- exact 4-way merge (pointer-walk; LDS dynamic index, regs static) ----
    float gv[KKEEP]; int gi[KKEEP];
    {
        int   hp0 = 0, hp1 = 0, hp2 = 0, hp3 = 0;
        float hv0 = Ls[0][lane][0], hv1 = Ls[1][lane][0],
              hv2 = Ls[2][lane][0], hv3 = Ls[3][lane][0];
        int   hi0 = Li[0][lane][0], hi1 = Li[1][lane][0],
              hi2 = Li[2][lane][0], hi3 = Li[3][lane][0];
        #pragma unroll
        for (int s = 0; s < KKEEP; ++s) {
            float bv = hv0; int bi = hi0; int bj = 0;
            if (hv1 > bv || (hv1 == bv && hi1 < bi)) { bv = hv1; bi = hi1; bj = 1; }
            if (hv2 > bv || (hv2 == bv && hi2 < bi)) { bv = hv2; bi = hi2; bj = 2; }
            if (hv3 > bv || (hv3 == bv && hi3 < bi)) { bv = hv3; bi = hi3; bj = 3; }
            gv[s] = bv; gi[s] = bi;
            // advance the winning list (branchless; clamp read, mask with -INF)
            {
                const bool a = (bj == 0); const int np = hp0 + (a ? 1 : 0);
                const int  rp = np < KKEEP ? np : KKEEP-1;
                const float nv = Ls[0][lane][rp]; const int ni = Li[0][lane][rp];
                if (a) { hp0 = np; hv0 = (np < KKEEP) ? nv : -INFINITY; hi0 = ni; }
            }
            {
                const bool a = (bj == 1); const int np = hp1 + (a ? 1 : 0);
                const int  rp = np < KKEEP ? np : KKEEP-1;
                const float nv = Ls[1][lane][rp]; const int ni = Li[1][lane][rp];
                if (a) { hp1 = np; hv1 = (np < KKEEP) ? nv : -INFINITY; hi1 = ni; }
            }
            {
                const bool a = (bj == 2); const int np = hp2 + (a ? 1 : 0);
                const int  rp = np < KKEEP ? np : KKEEP-1;
                const float nv = Ls[2][lane][rp]; const int ni = Li[2][lane][rp];
                if (a) { hp2 = np; hv2 = (np < KKEEP) ? nv : -INFINITY; hi2 = ni; }
            }
            {
                const bool a = (bj == 3); const int np = hp3 + (a ? 1 : 0);
                const int  rp = np < KKEEP ? np : KKEEP-1;
                const float nv = Ls[3][lane][rp]; const int ni = Li[3][lane][rp];
                if (a) { hp3 = np; hv3 = (np < KKEEP) ? nv : -INFINITY; hi3 = ni; }
            }
        }
    }

    // ---- per-lane softmax over kept set (identical order to R6-R11) ----
    const float thr = gv[KTOP-1];
    const float m   = gv[0];
    float wv[KKEEP]; float wsum = 0.f;
    #pragma unroll
    for (int s = 0; s < KKEEP; ++s) {
        wv[s] = (gv[s] >= thr) ? expf(gv[s] - m) : 0.f;   // slots 8,9 iff tied
        wsum += wv[s];
    }

    // ---- sparse PV, this wave does dims [w*16, w*16+16) ----
    float o[16];
    #pragma unroll
    for (int d = 0; d < 16; ++d) o[d] = 0.f;
    #pragma unroll
    for (int s = 0; s < KKEEP; ++s) {
        const float wgt = wv[s] / wsum;                  // 0 for non-kept: exact
        const float* vrow = V + (size_t)gi[s] * HDIM + w * 16;
        #pragma unroll
        for (int d4 = 0; d4 < 4; ++d4) {
            float4 vv = *(const float4*)(vrow + d4*4);
            o[d4*4+0] = fmaf(wgt, vv.x, o[d4*4+0]);
            o[d4*4+1] = fmaf(wgt, vv.y, o[d4*4+1]);
            o[d4*4+2] = fmaf(wgt, vv.z, o[d4*4+2]);
            o[d4*4+3] = fmaf(wgt, vv.w, o[d4*4+3]);
        }
    }

    // AO flat layout [b][s][h*64+d]
    float* dst = AO + ((size_t)(bh >> 4) * SEQ + srow) * DMODEL
               + (bh & 15) * HDIM + w * 16;
    #pragma unroll
    for (int d4 = 0; d4 < 4; ++d4) {
        float4 ov; ov.x = o[d4*4+0]; ov.y = o[d4*4+1];
                   ov.z = o[d4*4+2]; ov.w = o[d4*4+3];
        *(float4*)(dst + d4*4) = ov;
    }
}

// ---------------------------------------------------------------------------
extern "C" void kernel_launch(void* const* d_in, const int* in_sizes, int n_in,
                              void* d_out, int out_size, void* d_ws, size_t ws_size,
                              hipStream_t stream)
{
    const float* q  = (const float*)d_in[0];
    const float* k  = (const float*)d_in[1];
    const float* v  = (const float*)d_in[2];
    const float* Wq = (const float*)d_in[3];
    const float* bq = (const float*)d_in[4];
    const float* Wk = (const float*)d_in[5];
    const float* bk = (const float*)d_in[6];
    const float* Wv = (const float*)d_in[7];
    const float* bv = (const float*)d_in[8];
    const float* Wo = (const float*)d_in[9];
    const float* bo = (const float*)d_in[10];
    float* out = (float*)d_out;

    const size_t nH = (size_t)BATCH * NHEAD * SEQ * HDIM;  // 4,194,304
    float* Qh = (float*)d_ws;          // 16.78 MB
    float* Kh = Qh + nH;               // 16.78 MB
    float* Vh = Kh + nH;               // 16.78 MB
    float* AO = Vh + nH;               // 16.78 MB  (total ~67 MB)

    dim3 gg(64, 16), gb(256);
    hipLaunchKernelGGL((proj_gemm<0>), gg, gb, 0, stream, q, Wq, bq, Qh);
    hipLaunchKernelGGL((proj_gemm<0>), gg, gb, 0, stream, k, Wk, bk, Kh);
    hipLaunchKernelGGL((proj_gemm<0>), gg, gb, 0, stream, v, Wv, bv, Vh);
    hipLaunchKernelGGL(attn_topk, dim3(BATCH*NHEAD, SEQ/64), dim3(256), 0, stream,
                       Qh, Kh, Vh, AO);
    hipLaunchKernelGGL((proj_gemm<1>), gg, gb, 0, stream, AO, Wo, bo, out);
}

// Round 13
// 1848.141 us; speedup vs baseline: 1.1908x; 1.1908x over previous
//
#include <hip/hip_runtime.h>
#include <cmath>

#define BATCH  2
#define SEQ    2048
#define DMODEL 1024
#define NHEAD  16
#define HDIM   64
#define KTOP   8
#define KKEEP  10   // top-8 + slack for bitwise ties at the threshold

// KC=512 CONFIRMED bit-exact vs harness numpy reference (rounds 6/8-12 pass).
#define KC_PANEL 512

// ---------------------------------------------------------------------------
// Projection GEMM replicating OpenBLAS sgemm fp32 rounding (KC=512 panels).
// MODE 0: out in head layout [b][h][s][d]; MODE 1: flat [row][col].
// ---------------------------------------------------------------------------
template<int MODE>
__global__ __launch_bounds__(256)
void proj_gemm(const float* __restrict__ A, const float* __restrict__ W,
               const float* __restrict__ bias, float* __restrict__ outp)
{
    __shared__ float As[32][68];   // [k][m]
    __shared__ float Bs[32][68];   // [k][n]
    const int tid  = threadIdx.x;
    const int tx   = tid & 15, ty = tid >> 4;
    const int row0 = blockIdx.x * 64;
    const int col0 = blockIdx.y * 64;
    const int lm   = tid >> 2;          // 0..63
    const int lk   = (tid & 3) * 8;     // 0,8,16,24

    float acc[4][4] = {};   // open panel chain
    float sum[4][4] = {};   // closed panels

    for (int kb = 0; kb < DMODEL; kb += 32) {
        if (kb && (kb % KC_PANEL == 0)) {
            #pragma unroll
            for (int i = 0; i < 4; ++i)
                #pragma unroll
                for (int j = 0; j < 4; ++j) { sum[i][j] += acc[i][j]; acc[i][j] = 0.f; }
        }
        __syncthreads();
        const float* srcA = A + (size_t)(row0 + lm) * DMODEL + kb + lk;
        float4 a0 = *(const float4*)srcA;
        float4 a1 = *(const float4*)(srcA + 4);
        const float* srcB = W + (size_t)(col0 + lm) * DMODEL + kb + lk;
        float4 b0 = *(const float4*)srcB;
        float4 b1 = *(const float4*)(srcB + 4);
        As[lk+0][lm]=a0.x; As[lk+1][lm]=a0.y; As[lk+2][lm]=a0.z; As[lk+3][lm]=a0.w;
        As[lk+4][lm]=a1.x; As[lk+5][lm]=a1.y; As[lk+6][lm]=a1.z; As[lk+7][lm]=a1.w;
        Bs[lk+0][lm]=b0.x; Bs[lk+1][lm]=b0.y; Bs[lk+2][lm]=b0.z; Bs[lk+3][lm]=b0.w;
        Bs[lk+4][lm]=b1.x; Bs[lk+5][lm]=b1.y; Bs[lk+6][lm]=b1.z; Bs[lk+7][lm]=b1.w;
        __syncthreads();
        #pragma unroll
        for (int kk = 0; kk < 32; ++kk) {   // ascending k, fused-FMA chain
            float4 af = *(const float4*)&As[kk][ty*4];
            float4 bf = *(const float4*)&Bs[kk][tx*4];
            float a_[4] = {af.x, af.y, af.z, af.w};
            float b_[4] = {bf.x, bf.y, bf.z, bf.w};
            #pragma unroll
            for (int i = 0; i < 4; ++i)
                #pragma unroll
                for (int j = 0; j < 4; ++j)
                    acc[i][j] = fmaf(a_[i], b_[j], acc[i][j]);
        }
    }

    #pragma unroll
    for (int i = 0; i < 4; ++i) {
        const int row = row0 + ty*4 + i;
        const int bb  = row >> 11;
        const int ss  = row & (SEQ - 1);
        #pragma unroll
        for (int j = 0; j < 4; ++j) {
            const int col = col0 + tx*4 + j;
            float r = sum[i][j] + acc[i][j];   // close final panel
            r = r + bias[col];                 // bias == 0.0f: exact
            if constexpr (MODE == 1) {
                outp[(size_t)row * DMODEL + col] = r;
            } else {
                const int h = col >> 6, d = col & 63;
                outp[(((size_t)(bb*NHEAD + h))*SEQ + ss)*HDIM + d] = r;
            }
        }
    }
}

// ---------------------------------------------------------------------------
// Attention, lane = query row, waves split keys 4-way (R12 structure), plus:
//  * __launch_bounds__(256,2): VGPR cap 256 >= ~225 live -> NO SPILL.
//    (R12's (256,4) cap-128 allocator spilled q to scratch: VGPR=64,
//    WRITE_SIZE 35MB, VALUBusy 35%. R8/R10 same failure mode.)
//  * Explicit double-buffered key prefetch (bufA/bufB, manual 2x unroll):
//    key c+1's 16 broadcast float4 loads issue BEFORE key c's cascade ->
//    ~200-300cyc L2 latency hides under ~256cyc VALU. ILP instead of TLP.
// Selection/merge/PV identical to R12 (passed, bit-exact): lane-local
// ascending-order insert per 512-key range, exact 4-way merge with
// (value, lower-index) comparator, softmax over kept set, dim-split PV.
// ---------------------------------------------------------------------------
__global__ __launch_bounds__(256, 2)
void attn_topk(const float* __restrict__ Qh, const float* __restrict__ Kh,
               const float* __restrict__ Vh, float* __restrict__ AO)
{
    __shared__ float Ls[4][64][KKEEP + 1];   // +1 pad: 11*4B lane stride
    __shared__ int   Li[4][64][KKEEP + 1];
    const int tid  = threadIdx.x;
    const int lane = tid & 63;
    const int w    = tid >> 6;          // 0..3 (key quarter / dim quarter)
    const int bh   = blockIdx.x;        // 0..31  (XCD = bh % 8)
    const int rg   = blockIdx.y;        // 0..31
    const int srow = rg * 64 + lane;    // this lane's query row
    const size_t hbase = (size_t)bh * SEQ * HDIM;
    const float* Q = Qh + hbase;
    const float* K = Kh + hbase;
    const float* V = Vh + hbase;

    // ---- this lane's q row -> VGPRs ----
    float q[64];
    {
        const float* qsrc = Q + (size_t)srow * HDIM;
        #pragma unroll
        for (int d4 = 0; d4 < 16; ++d4) {
            float4 t4 = *(const float4*)(qsrc + d4*4);
            q[d4*4+0]=t4.x; q[d4*4+1]=t4.y; q[d4*4+2]=t4.z; q[d4*4+3]=t4.w;
        }
    }

    // ---- lane-local top-KKEEP over this wave's 512-key range ----
    float tv[KKEEP]; int ti[KKEEP];
    #pragma unroll
    for (int s = 0; s < KKEEP; ++s) { tv[s] = -INFINITY; ti[s] = -1; }

    const int k0 = w * (SEQ/4);

#define LOADKEY(buf, kidx)                                                  \
    do {                                                                    \
        const float* kb_ = K + (size_t)(kidx) * HDIM;                       \
        _Pragma("unroll")                                                   \
        for (int f_ = 0; f_ < 16; ++f_)                                     \
            buf[f_] = *(const float4*)(kb_ + 4*f_);                         \
    } while (0)

#define DOTINS(buf, kidx)                                                   \
    do {                                                                    \
        float raw_;                                                         \
        {                                                                   \
            _Pragma("clang fp contract(off)")                               \
            float A0=0.f, A1=0.f, A2=0.f, A3=0.f;                           \
            _Pragma("unroll")                                               \
            for (int t_ = 0; t_ < 4; ++t_) {                                \
                float kv[16];                                               \
                _Pragma("unroll")                                           \
                for (int f_ = 0; f_ < 4; ++f_) {                            \
                    kv[f_*4+0] = buf[t_*4+f_].x;                            \
                    kv[f_*4+1] = buf[t_*4+f_].y;                            \
                    kv[f_*4+2] = buf[t_*4+f_].z;                            \
                    kv[f_*4+3] = buf[t_*4+f_].w;                            \
                }                                                           \
                const int u_ = t_*16;                                       \
                A0 = q[u_+0]*kv[0] + (q[u_+4]*kv[4] + (q[u_+8]*kv[8]   + (q[u_+12]*kv[12] + A0))); \
                A1 = q[u_+1]*kv[1] + (q[u_+5]*kv[5] + (q[u_+9]*kv[9]   + (q[u_+13]*kv[13] + A1))); \
                A2 = q[u_+2]*kv[2] + (q[u_+6]*kv[6] + (q[u_+10]*kv[10] + (q[u_+14]*kv[14] + A2))); \
                A3 = q[u_+3]*kv[3] + (q[u_+7]*kv[7] + (q[u_+11]*kv[11] + (q[u_+15]*kv[15] + A3))); \
            }                                                               \
            raw_ = (A0 + A1) + (A2 + A3);                                   \
        }                                                                   \
        const float cand_ = raw_ * 0.125f;      /* /sqrt(64) exact */       \
        if (cand_ > tv[KKEEP-1]) {              /* lane-local insert */     \
            float v_ = cand_; int ix_ = (kidx);                             \
            _Pragma("unroll")                                               \
            for (int s_ = 0; s_ < KKEEP; ++s_) {                            \
                const bool gt_ = v_ > tv[s_];                               \
                const float otv_ = tv[s_]; const int oti_ = ti[s_];         \
                tv[s_] = gt_ ? v_  : otv_;  ti[s_] = gt_ ? ix_  : oti_;     \
                v_     = gt_ ? otv_ : v_;   ix_    = gt_ ? oti_ : ix_;      \
            }                                                               \
        }                                                                   \
    } while (0)

    {
        float4 bufA[16], bufB[16];
        LOADKEY(bufA, k0);                       // prologue: key 0
        for (int c = 0; c < SEQ/4; c += 2) {
            const int c1 = k0 + ((c+1 < SEQ/4) ? c+1 : SEQ/4-1);
            const int c2 = k0 + ((c+2 < SEQ/4) ? c+2 : SEQ/4-1);
            LOADKEY(bufB, c1);                   // issue c+1 loads ...
            DOTINS(bufA, k0 + c);                // ... under c's compute
            LOADKEY(bufA, c2);                   // issue c+2 loads ...
            DOTINS(bufB, c1);                    // ... under c+1's compute
        }
    }
#undef LOADKEY
#undef DOTINS

    // ---- publish partial lists, one barrier ----
    #pragma unroll
    for (int s = 0; s < KKEEP; ++s) {
        Ls[w][lane][s] = tv[s];
        Li[w][lane][s] = ti[s];
    }
    __syncthreads();

    // ---- exact 4-way merge (pointer-walk; LDS dynamic index, regs static) ----
    float gv[KKEEP]; int gi[KKEEP];
    {
        int   hp0 = 0, hp1 = 0, hp2 = 0, hp3 = 0;
        float hv0 = Ls[0][lane][0], hv1 = Ls[1][lane][0],
              hv2 = Ls[2][lane][0], hv3 = Ls[3][lane][0];
        int   hi0 = Li[0][lane][0], hi1 = Li[1][lane][0],
              hi2 = Li[2][lane][0], hi3 = Li[3][lane][0];
        #pragma unroll
        for (int s = 0; s < KKEEP; ++s) {
            float bv = hv0; int bi = hi0; int bj = 0;
            if (hv1 > bv || (hv1 == bv && hi1 < bi)) { bv = hv1; bi = hi1; bj = 1; }
            if (hv2 > bv || (hv2 == bv && hi2 < bi)) { bv = hv2; bi = hi2; bj = 2; }
            if (hv3 > bv || (hv3 == bv && hi3 < bi)) { bv = hv3; bi = hi3; bj = 3; }
            gv[s] = bv; gi[s] = bi;
            {
                const bool a = (bj == 0); const int np = hp0 + (a ? 1 : 0);
                const int  rp = np < KKEEP ? np : KKEEP-1;
                const float nv = Ls[0][lane][rp]; const int ni = Li[0][lane][rp];
                if (a) { hp0 = np; hv0 = (np < KKEEP) ? nv : -INFINITY; hi0 = ni; }
            }
            {
                const bool a = (bj == 1); const int np = hp1 + (a ? 1 : 0);
                const int  rp = np < KKEEP ? np : KKEEP-1;
                const float nv = Ls[1][lane][rp]; const int ni = Li[1][lane][rp];
                if (a) { hp1 = np; hv1 = (np < KKEEP) ? nv : -INFINITY; hi1 = ni; }
            }
            {
                const bool a = (bj == 2); const int np = hp2 + (a ? 1 : 0);
                const int  rp = np < KKEEP ? np : KKEEP-1;
                const float nv = Ls[2][lane][rp]; const int ni = Li[2][lane][rp];
                if (a) { hp2 = np; hv2 = (np < KKEEP) ? nv : -INFINITY; hi2 = ni; }
            }
            {
                const bool a = (bj == 3); const int np = hp3 + (a ? 1 : 0);
                const int  rp = np < KKEEP ? np : KKEEP-1;
                const float nv = Ls[3][lane][rp]; const int ni = Li[3][lane][rp];
                if (a) { hp3 = np; hv3 = (np < KKEEP) ? nv : -INFINITY; hi3 = ni; }
            }
        }
    }

    // ---- per-lane softmax over kept set (identical order to R6-R12) ----
    const float thr = gv[KTOP-1];
    const float m   = gv[0];
    float wv[KKEEP]; float wsum = 0.f;
    #pragma unroll
    for (int s = 0; s < KKEEP; ++s) {
        wv[s] = (gv[s] >= thr) ? expf(gv[s] - m) : 0.f;   // slots 8,9 iff tied
        wsum += wv[s];
    }

    // ---- sparse PV, this wave does dims [w*16, w*16+16) ----
    float o[16];
    #pragma unroll
    for (int d = 0; d < 16; ++d) o[d] = 0.f;
    #pragma unroll
    for (int s = 0; s < KKEEP; ++s) {
        const float wgt = wv[s] / wsum;                  // 0 for non-kept: exact
        const float* vrow = V + (size_t)gi[s] * HDIM + w * 16;
        #pragma unroll
        for (int d4 = 0; d4 < 4; ++d4) {
            float4 vv = *(const float4*)(vrow + d4*4);
            o[d4*4+0] = fmaf(wgt, vv.x, o[d4*4+0]);
            o[d4*4+1] = fmaf(wgt, vv.y, o[d4*4+1]);
            o[d4*4+2] = fmaf(wgt, vv.z, o[d4*4+2]);
            o[d4*4+3] = fmaf(wgt, vv.w, o[d4*4+3]);
        }
    }

    // AO flat layout [b][s][h*64+d]
    float* dst = AO + ((size_t)(bh >> 4) * SEQ + srow) * DMODEL
               + (bh & 15) * HDIM + w * 16;
    #pragma unroll
    for (int d4 = 0; d4 < 4; ++d4) {
        float4 ov; ov.x = o[d4*4+0]; ov.y = o[d4*4+1];
                   ov.z = o[d4*4+2]; ov.w = o[d4*4+3];
        *(float4*)(dst + d4*4) = ov;
    }
}

// ---------------------------------------------------------------------------
extern "C" void kernel_launch(void* const* d_in, const int* in_sizes, int n_in,
                              void* d_out, int out_size, void* d_ws, size_t ws_size,
                              hipStream_t stream)
{
    const float* q  = (const float*)d_in[0];
    const float* k  = (const float*)d_in[1];
    const float* v  = (const float*)d_in[2];
    const float* Wq = (const float*)d_in[3];
    const float* bq = (const float*)d_in[4];
    const float* Wk = (const float*)d_in[5];
    const float* bk = (const float*)d_in[6];
    const float* Wv = (const float*)d_in[7];
    const float* bv = (const float*)d_in[8];
    const float* Wo = (const float*)d_in[9];
    const float* bo = (const float*)d_in[10];
    float* out = (float*)d_out;

    const size_t nH = (size_t)BATCH * NHEAD * SEQ * HDIM;  // 4,194,304
    float* Qh = (float*)d_ws;          // 16.78 MB
    float* Kh = Qh + nH;               // 16.78 MB
    float* Vh = Kh + nH;               // 16.78 MB
    float* AO = Vh + nH;               // 16.78 MB  (total ~67 MB)

    dim3 gg(64, 16), gb(256);
    hipLaunchKernelGGL((proj_gemm<0>), gg, gb, 0, stream, q, Wq, bq, Qh);
    hipLaunchKernelGGL((proj_gemm<0>), gg, gb, 0, stream, k, Wk, bk, Kh);
    hipLaunchKernelGGL((proj_gemm<0>), gg, gb, 0, stream, v, Wv, bv, Vh);
    hipLaunchKernelGGL(attn_topk, dim3(BATCH*NHEAD, SEQ/64), dim3(256), 0, stream,
                       Qh, Kh, Vh, AO);
    hipLaunchKernelGGL((proj_gemm<1>), gg, gb, 0, stream, AO, Wo, bo, out);
}

// Round 14
// 1501.951 us; speedup vs baseline: 1.4652x; 1.2305x over previous
//
#include <hip/hip_runtime.h>
#include <cmath>

#define BATCH  2
#define SEQ    2048
#define DMODEL 1024
#define NHEAD  16
#define HDIM   64
#define KTOP   8
#define KKEEP  10   // top-8 + slack for bitwise ties at the threshold

// KC=512 CONFIRMED bit-exact vs harness numpy reference (rounds 6/8-13 pass).
#define KC_PANEL 512

// ---------------------------------------------------------------------------
// Projection GEMM replicating OpenBLAS sgemm fp32 rounding (KC=512 panels).
// MODE 0: out in head layout [b][h][s][d]; MODE 1: flat [row][col].
// ---------------------------------------------------------------------------
template<int MODE>
__global__ __launch_bounds__(256)
void proj_gemm(const float* __restrict__ A, const float* __restrict__ W,
               const float* __restrict__ bias, float* __restrict__ outp)
{
    __shared__ float As[32][68];   // [k][m]
    __shared__ float Bs[32][68];   // [k][n]
    const int tid  = threadIdx.x;
    const int tx   = tid & 15, ty = tid >> 4;
    const int row0 = blockIdx.x * 64;
    const int col0 = blockIdx.y * 64;
    const int lm   = tid >> 2;          // 0..63
    const int lk   = (tid & 3) * 8;     // 0,8,16,24

    float acc[4][4] = {};   // open panel chain
    float sum[4][4] = {};   // closed panels

    for (int kb = 0; kb < DMODEL; kb += 32) {
        if (kb && (kb % KC_PANEL == 0)) {
            #pragma unroll
            for (int i = 0; i < 4; ++i)
                #pragma unroll
                for (int j = 0; j < 4; ++j) { sum[i][j] += acc[i][j]; acc[i][j] = 0.f; }
        }
        __syncthreads();
        const float* srcA = A + (size_t)(row0 + lm) * DMODEL + kb + lk;
        float4 a0 = *(const float4*)srcA;
        float4 a1 = *(const float4*)(srcA + 4);
        const float* srcB = W + (size_t)(col0 + lm) * DMODEL + kb + lk;
        float4 b0 = *(const float4*)srcB;
        float4 b1 = *(const float4*)(srcB + 4);
        As[lk+0][lm]=a0.x; As[lk+1][lm]=a0.y; As[lk+2][lm]=a0.z; As[lk+3][lm]=a0.w;
        As[lk+4][lm]=a1.x; As[lk+5][lm]=a1.y; As[lk+6][lm]=a1.z; As[lk+7][lm]=a1.w;
        Bs[lk+0][lm]=b0.x; Bs[lk+1][lm]=b0.y; Bs[lk+2][lm]=b0.z; Bs[lk+3][lm]=b0.w;
        Bs[lk+4][lm]=b1.x; Bs[lk+5][lm]=b1.y; Bs[lk+6][lm]=b1.z; Bs[lk+7][lm]=b1.w;
        __syncthreads();
        #pragma unroll
        for (int kk = 0; kk < 32; ++kk) {   // ascending k, fused-FMA chain
            float4 af = *(const float4*)&As[kk][ty*4];
            float4 bf = *(const float4*)&Bs[kk][tx*4];
            float a_[4] = {af.x, af.y, af.z, af.w};
            float b_[4] = {bf.x, bf.y, bf.z, bf.w};
            #pragma unroll
            for (int i = 0; i < 4; ++i)
                #pragma unroll
                for (int j = 0; j < 4; ++j)
                    acc[i][j] = fmaf(a_[i], b_[j], acc[i][j]);
        }
    }

    #pragma unroll
    for (int i = 0; i < 4; ++i) {
        const int row = row0 + ty*4 + i;
        const int bb  = row >> 11;
        const int ss  = row & (SEQ - 1);
        #pragma unroll
        for (int j = 0; j < 4; ++j) {
            const int col = col0 + tx*4 + j;
            float r = sum[i][j] + acc[i][j];   // close final panel
            r = r + bias[col];                 // bias == 0.0f: exact
            if constexpr (MODE == 1) {
                outp[(size_t)row * DMODEL + col] = r;
            } else {
                const int h = col >> 6, d = col & 63;
                outp[(((size_t)(bb*NHEAD + h))*SEQ + ss)*HDIM + d] = r;
            }
        }
    }
}

// ---------------------------------------------------------------------------
// Attention, lane = query row, waves split keys 4-way, explicit 2-deep key
// prefetch (R13 structure). ONE change vs R13: __launch_bounds__(256, 1).
//   R13's (256,2) let the allocator target 4 waves/SIMD -> cap 128 VGPR ->
//   spilled the ~230-reg live set (q[64] + bufA/bufB 128): WRITE_SIZE 32MB,
//   VALUBusy 44%. R9 precedent: (256,1) -> allocator gives the live set
//   (148 there), zero spill. Here ~230 fits the 256 cap; VGPR pool 512/lane
//   per SIMD still gives 2 waves/SIMD -> prefetch + 2-wave TLP covers L2
//   latency without scratch.
// Selection/merge/PV identical to R12/R13 (passed, bit-exact).
// ---------------------------------------------------------------------------
__global__ __launch_bounds__(256, 1)
void attn_topk(const float* __restrict__ Qh, const float* __restrict__ Kh,
               const float* __restrict__ Vh, float* __restrict__ AO)
{
    __shared__ float Ls[4][64][KKEEP + 1];   // +1 pad: 11*4B lane stride
    __shared__ int   Li[4][64][KKEEP + 1];
    const int tid  = threadIdx.x;
    const int lane = tid & 63;
    const int w    = tid >> 6;          // 0..3 (key quarter / dim quarter)
    const int bh   = blockIdx.x;        // 0..31  (XCD = bh % 8)
    const int rg   = blockIdx.y;        // 0..31
    const int srow = rg * 64 + lane;    // this lane's query row
    const size_t hbase = (size_t)bh * SEQ * HDIM;
    const float* Q = Qh + hbase;
    const float* K = Kh + hbase;
    const float* V = Vh + hbase;

    // ---- this lane's q row -> VGPRs ----
    float q[64];
    {
        const float* qsrc = Q + (size_t)srow * HDIM;
        #pragma unroll
        for (int d4 = 0; d4 < 16; ++d4) {
            float4 t4 = *(const float4*)(qsrc + d4*4);
            q[d4*4+0]=t4.x; q[d4*4+1]=t4.y; q[d4*4+2]=t4.z; q[d4*4+3]=t4.w;
        }
    }

    // ---- lane-local top-KKEEP over this wave's 512-key range ----
    float tv[KKEEP]; int ti[KKEEP];
    #pragma unroll
    for (int s = 0; s < KKEEP; ++s) { tv[s] = -INFINITY; ti[s] = -1; }

    const int k0 = w * (SEQ/4);

#define LOADKEY(buf, kidx)                                                  \
    do {                                                                    \
        const float* kb_ = K + (size_t)(kidx) * HDIM;                       \
        _Pragma("unroll")                                                   \
        for (int f_ = 0; f_ < 16; ++f_)                                     \
            buf[f_] = *(const float4*)(kb_ + 4*f_);                         \
    } while (0)

#define DOTINS(buf, kidx)                                                   \
    do {                                                                    \
        float raw_;                                                         \
        {                                                                   \
            _Pragma("clang fp contract(off)")                               \
            float A0=0.f, A1=0.f, A2=0.f, A3=0.f;                           \
            _Pragma("unroll")                                               \
            for (int t_ = 0; t_ < 4; ++t_) {                                \
                float kv[16];                                               \
                _Pragma("unroll")                                           \
                for (int f_ = 0; f_ < 4; ++f_) {                            \
                    kv[f_*4+0] = buf[t_*4+f_].x;                            \
                    kv[f_*4+1] = buf[t_*4+f_].y;                            \
                    kv[f_*4+2] = buf[t_*4+f_].z;                            \
                    kv[f_*4+3] = buf[t_*4+f_].w;                            \
                }                                                           \
                const int u_ = t_*16;                                       \
                A0 = q[u_+0]*kv[0] + (q[u_+4]*kv[4] + (q[u_+8]*kv[8]   + (q[u_+12]*kv[12] + A0))); \
                A1 = q[u_+1]*kv[1] + (q[u_+5]*kv[5] + (q[u_+9]*kv[9]   + (q[u_+13]*kv[13] + A1))); \
                A2 = q[u_+2]*kv[2] + (q[u_+6]*kv[6] + (q[u_+10]*kv[10] + (q[u_+14]*kv[14] + A2))); \
                A3 = q[u_+3]*kv[3] + (q[u_+7]*kv[7] + (q[u_+11]*kv[11] + (q[u_+15]*kv[15] + A3))); \
            }                                                               \
            raw_ = (A0 + A1) + (A2 + A3);                                   \
        }                                                                   \
        const float cand_ = raw_ * 0.125f;      /* /sqrt(64) exact */       \
        if (cand_ > tv[KKEEP-1]) {              /* lane-local insert */     \
            float v_ = cand_; int ix_ = (kidx);                             \
            _Pragma("unroll")                                               \
            for (int s_ = 0; s_ < KKEEP; ++s_) {                            \
                const bool gt_ = v_ > tv[s_];                               \
                const float otv_ = tv[s_]; const int oti_ = ti[s_];         \
                tv[s_] = gt_ ? v_  : otv_;  ti[s_] = gt_ ? ix_  : oti_;     \
                v_     = gt_ ? otv_ : v_;   ix_    = gt_ ? oti_ : ix_;      \
            }                                                               \
        }                                                                   \
    } while (0)

    {
        float4 bufA[16], bufB[16];
        LOADKEY(bufA, k0);                       // prologue: key 0
        for (int c = 0; c < SEQ/4; c += 2) {
            const int c1 = k0 + ((c+1 < SEQ/4) ? c+1 : SEQ/4-1);
            const int c2 = k0 + ((c+2 < SEQ/4) ? c+2 : SEQ/4-1);
            LOADKEY(bufB, c1);                   // issue c+1 loads ...
            DOTINS(bufA, k0 + c);                // ... under c's compute
            LOADKEY(bufA, c2);                   // issue c+2 loads ...
            DOTINS(bufB, c1);                    // ... under c+1's compute
        }
    }
#undef LOADKEY
#undef DOTINS

    // ---- publish partial lists, one barrier ----
    #pragma unroll
    for (int s = 0; s < KKEEP; ++s) {
        Ls[w][lane][s] = tv[s];
        Li[w][lane][s] = ti[s];
    }
    __syncthreads();

    // ---- exact 4-way merge (pointer-walk; LDS dynamic index, regs static) ----
    float gv[KKEEP]; int gi[KKEEP];
    {
        int   hp0 = 0, hp1 = 0, hp2 = 0, hp3 = 0;
        float hv0 = Ls[0][lane][0], hv1 = Ls[1][lane][0],
              hv2 = Ls[2][lane][0], hv3 = Ls[3][lane][0];
        int   hi0 = Li[0][lane][0], hi1 = Li[1][lane][0],
              hi2 = Li[2][lane][0], hi3 = Li[3][lane][0];
        #pragma unroll
        for (int s = 0; s < KKEEP; ++s) {
            float bv = hv0; int bi = hi0; int bj = 0;
            if (hv1 > bv || (hv1 == bv && hi1 < bi)) { bv = hv1; bi = hi1; bj = 1; }
            if (hv2 > bv || (hv2 == bv && hi2 < bi)) { bv = hv2; bi = hi2; bj = 2; }
            if (hv3 > bv || (hv3 == bv && hi3 < bi)) { bv = hv3; bi = hi3; bj = 3; }
            gv[s] = bv; gi[s] = bi;
            {
                const bool a = (bj == 0); const int np = hp0 + (a ? 1 : 0);
                const int  rp = np < KKEEP ? np : KKEEP-1;
                const float nv = Ls[0][lane][rp]; const int ni = Li[0][lane][rp];
                if (a) { hp0 = np; hv0 = (np < KKEEP) ? nv : -INFINITY; hi0 = ni; }
            }
            {
                const bool a = (bj == 1); const int np = hp1 + (a ? 1 : 0);
                const int  rp = np < KKEEP ? np : KKEEP-1;
                const float nv = Ls[1][lane][rp]; const int ni = Li[1][lane][rp];
                if (a) { hp1 = np; hv1 = (np < KKEEP) ? nv : -INFINITY; hi1 = ni; }
            }
            {
                const bool a = (bj == 2); const int np = hp2 + (a ? 1 : 0);
                const int  rp = np < KKEEP ? np : KKEEP-1;
                const float nv = Ls[2][lane][rp]; const int ni = Li[2][lane][rp];
                if (a) { hp2 = np; hv2 = (np < KKEEP) ? nv : -INFINITY; hi2 = ni; }
            }
            {
                const bool a = (bj == 3); const int np = hp3 + (a ? 1 : 0);
                const int  rp = np < KKEEP ? np : KKEEP-1;
                const float nv = Ls[3][lane][rp]; const int ni = Li[3][lane][rp];
                if (a) { hp3 = np; hv3 = (np < KKEEP) ? nv : -INFINITY; hi3 = ni; }
            }
        }
    }

    // ---- per-lane softmax over kept set (identical order to R6-R13) ----
    const float thr = gv[KTOP-1];
    const float m   = gv[0];
    float wv[KKEEP]; float wsum = 0.f;
    #pragma unroll
    for (int s = 0; s < KKEEP; ++s) {
        wv[s] = (gv[s] >= thr) ? expf(gv[s] - m) : 0.f;   // slots 8,9 iff tied
        wsum += wv[s];
    }

    // ---- sparse PV, this wave does dims [w*16, w*16+16) ----
    float o[16];
    #pragma unroll
    for (int d = 0; d < 16; ++d) o[d] = 0.f;
    #pragma unroll
    for (int s = 0; s < KKEEP; ++s) {
        const float wgt = wv[s] / wsum;                  // 0 for non-kept: exact
        const float* vrow = V + (size_t)gi[s] * HDIM + w * 16;
        #pragma unroll
        for (int d4 = 0; d4 < 4; ++d4) {
            float4 vv = *(const float4*)(vrow + d4*4);
            o[d4*4+0] = fmaf(wgt, vv.x, o[d4*4+0]);
            o[d4*4+1] = fmaf(wgt, vv.y, o[d4*4+1]);
            o[d4*4+2] = fmaf(wgt, vv.z, o[d4*4+2]);
            o[d4*4+3] = fmaf(wgt, vv.w, o[d4*4+3]);
        }
    }

    // AO flat layout [b][s][h*64+d]
    float* dst = AO + ((size_t)(bh >> 4) * SEQ + srow) * DMODEL
               + (bh & 15) * HDIM + w * 16;
    #pragma unroll
    for (int d4 = 0; d4 < 4; ++d4) {
        float4 ov; ov.x = o[d4*4+0]; ov.y = o[d4*4+1];
                   ov.z = o[d4*4+2]; ov.w = o[d4*4+3];
        *(float4*)(dst + d4*4) = ov;
    }
}

// ---------------------------------------------------------------------------
extern "C" void kernel_launch(void* const* d_in, const int* in_sizes, int n_in,
                              void* d_out, int out_size, void* d_ws, size_t ws_size,
                              hipStream_t stream)
{
    const float* q  = (const float*)d_in[0];
    const float* k  = (const float*)d_in[1];
    const float* v  = (const float*)d_in[2];
    const float* Wq = (const float*)d_in[3];
    const float* bq = (const float*)d_in[4];
    const float* Wk = (const float*)d_in[5];
    const float* bk = (const float*)d_in[6];
    const float* Wv = (const float*)d_in[7];
    const float* bv = (const float*)d_in[8];
    const float* Wo = (const float*)d_in[9];
    const float* bo = (const float*)d_in[10];
    float* out = (float*)d_out;

    const size_t nH = (size_t)BATCH * NHEAD * SEQ * HDIM;  // 4,194,304
    float* Qh = (float*)d_ws;          // 16.78 MB
    float* Kh = Qh + nH;               // 16.78 MB
    float* Vh = Kh + nH;               // 16.78 MB
    float* AO = Vh + nH;               // 16.78 MB  (total ~67 MB)

    dim3 gg(64, 16), gb(256);
    hipLaunchKernelGGL((proj_gemm<0>), gg, gb, 0, stream, q, Wq, bq, Qh);
    hipLaunchKernelGGL((proj_gemm<0>), gg, gb, 0, stream, k, Wk, bk, Kh);
    hipLaunchKernelGGL((proj_gemm<0>), gg, gb, 0, stream, v, Wv, bv, Vh);
    hipLaunchKernelGGL(attn_topk, dim3(BATCH*NHEAD, SEQ/64), dim3(256), 0, stream,
                       Qh, Kh, Vh, AO);
    hipLaunchKernelGGL((proj_gemm<1>), gg, gb, 0, stream, AO, Wo, bo, out);
}